// Round 3
// baseline (145.093 us; speedup 1.0000x reference)
//
#include <hip/hip_runtime.h>

#define BB 32
#define CC 384
#define TP 512
#define TF 2048
#define NJ 24   // stream blocks per batch; each owns 16 c-rows

__device__ __forceinline__ int imax(int a, int b) { return a > b ? a : b; }
__device__ __forceinline__ int imin(int a, int b) { return a < b ? a : b; }

// Single kernel, grid (NJ, BB) = 768 blocks = exactly 3/CU (all co-resident).
// Every block is a stream block for 16 c-rows AND computes the 4-output GEMV
// partial for its rows from the LDS-staged x (split-K by 24). Partials go to
// d_ws (nontemporal stores), release-fence + per-batch arrival counter; the
// 24th arriver for batch b reduces partials and writes ldp/lcp/vup/epp using
// its own po16/pm_s. This removes the old 8 GEMV blocks/batch and their
// 25 MB re-read of x. Counters are zeroed per launch by an in-graph memset.
__global__ __launch_bounds__(256, 3) void mono_kernel(
    const float* __restrict__ x, const float* __restrict__ phone_mask,
    const float* __restrict__ frame_mask, const int* __restrict__ duration,
    const float* __restrict__ log_cf0, const float* __restrict__ energy,
    const float* __restrict__ dur_w, const float* __restrict__ dur_b,
    const float* __restrict__ pitch_w, const float* __restrict__ pitch_b,
    const float* __restrict__ pemb_w, const float* __restrict__ pemb_b,
    const float* __restrict__ enp_w, const float* __restrict__ enp_b,
    const float* __restrict__ eemb_w, const float* __restrict__ eemb_b,
    float* __restrict__ ws_part, int* __restrict__ ws_ctr,
    float* __restrict__ out, float* __restrict__ ldp, float* __restrict__ lcp,
    float* __restrict__ vup, float* __restrict__ epp) {
    int j = blockIdx.x;
    int b = blockIdx.y;
    int tid = threadIdx.x;
    int lane = tid & 63;
    int wv = tid >> 6;  // 0..3
    const float* xb = x + (size_t)b * CC * TP;

    __shared__ float xs[16 * TP];  // 32 KB raw x rows
    __shared__ short po16[TF];     // 4 KB frame->phone
    __shared__ int ps[256];        // 1 KB pair-scan
    __shared__ float pm_s[TP];     // 2 KB phone_mask row
    __shared__ float y_s[4 * TP];  // 8 KB finisher reduction target
    __shared__ int amLast;

    int c0 = __builtin_amdgcn_readfirstlane(j * 16);
    const float* src = xb + (size_t)c0 * TP;
    // linear staging: conflict-free LDS writes, coalesced 1 KB/wave-instr reads
#pragma unroll
    for (int q = 0; q < 8; ++q) {
        int off = q * 1024 + tid * 4;
        *(float4*)(xs + off) = *(const float4*)(src + off);
    }
    int2 d01 = *(const int2*)(duration + b * TP + 2 * tid);
    int d0 = d01.x, d1 = d01.y;
    ps[tid] = d0 + d1;
    pm_s[tid] = phone_mask[b * TP + tid];
    pm_s[tid + 256] = phone_mask[b * TP + tid + 256];
#pragma unroll
    for (int h = 0; h < 4; ++h) ((int*)po16)[tid + 256 * h] = -1;  // two -1 shorts
    __syncthreads();
    for (int off = 1; off < 256; off <<= 1) {
        int v = (tid >= off) ? ps[tid - off] : 0;
        __syncthreads();
        ps[tid] += v;
        __syncthreads();
    }
    int excl = tid ? ps[tid - 1] : 0;
    int e0 = imin(excl + d0, TF);
    int e1 = imin(excl + d0 + d1, TF);
    for (int f = imin(excl, TF); f < e0; ++f) po16[f] = (short)(2 * tid);
    for (int f = e0; f < e1; ++f) po16[f] = (short)(2 * tid + 1);

    // ---- split-K GEMV partial over this block's 16 rows (xs is raw x) ----
    float a00 = 0.f, a01 = 0.f, a02 = 0.f, a03 = 0.f;
    float a10 = 0.f, a11 = 0.f, a12 = 0.f, a13 = 0.f;
#pragma unroll
    for (int r = 0; r < 16; ++r) {
        int c = c0 + r;  // uniform -> scalar weight loads
        float w0 = pitch_w[c], w1 = pitch_w[CC + c], w2 = enp_w[c], w3 = dur_w[c];
        float v0 = xs[r * TP + tid];
        float v1 = xs[r * TP + tid + 256];
        a00 = __builtin_fmaf(v0, w0, a00); a01 = __builtin_fmaf(v0, w1, a01);
        a02 = __builtin_fmaf(v0, w2, a02); a03 = __builtin_fmaf(v0, w3, a03);
        a10 = __builtin_fmaf(v1, w0, a10); a11 = __builtin_fmaf(v1, w1, a11);
        a12 = __builtin_fmaf(v1, w2, a12); a13 = __builtin_fmaf(v1, w3, a13);
    }
    {
        float* wp = ws_part + (size_t)(b * NJ + j) * 4 * TP;
        __builtin_nontemporal_store(a00, wp + 0 * TP + tid);
        __builtin_nontemporal_store(a01, wp + 1 * TP + tid);
        __builtin_nontemporal_store(a02, wp + 2 * TP + tid);
        __builtin_nontemporal_store(a03, wp + 3 * TP + tid);
        __builtin_nontemporal_store(a10, wp + 0 * TP + tid + 256);
        __builtin_nontemporal_store(a11, wp + 1 * TP + tid + 256);
        __builtin_nontemporal_store(a12, wp + 2 * TP + tid + 256);
        __builtin_nontemporal_store(a13, wp + 3 * TP + tid + 256);
    }
    __threadfence();    // release: partials visible device-wide
    __syncthreads();    // all threads fenced before tid0's atomic; po16 ready
    if (tid == 0) {
        int old = atomicAdd(&ws_ctr[b], 1);
        amLast = (old == NJ - 1);
    }
    __syncthreads();

    if (amLast) {  // block-uniform branch
        __threadfence();  // acquire: invalidate stale local cache lines
        for (int e = tid; e < 4 * TP; e += 256) {
            const float* p = ws_part + (size_t)b * NJ * 4 * TP + e;
            float a = 0.f;
#pragma unroll
            for (int jb = 0; jb < NJ; ++jb) a += p[(size_t)jb * 4 * TP];
            y_s[e] = a;
        }
        __syncthreads();
        float db = dur_b[0], pb0 = pitch_b[0], pb1 = pitch_b[1], eb = enp_b[0];
        for (int t = tid; t < TP; t += 256)
            ldp[b * TP + t] = (y_s[3 * TP + t] + db) * pm_s[t];
        const float* fm_b2 = frame_mask + (size_t)b * TF;
        for (int f = tid; f < TF; f += 256) {
            float fm = fm_b2[f];
            int p = po16[f];
            int pc = imax(p, 0);
            float xm = (p >= 0 ? pm_s[pc] : 0.f) * fm;
            lcp[b * TF + f] = (y_s[pc] * xm + pb0) * fm;
            vup[b * TF + f] = (y_s[TP + pc] * xm + pb1) * fm;
            epp[b * TF + f] = (y_s[2 * TP + pc] * xm + eb) * fm;
        }
    }

    // ---- main streaming loop: 16 rows x 2048 frames of out ----
    float wA[16], wB[16], wC[16];
#pragma unroll
    for (int r = 0; r < 16; ++r) {
        wA[r] = pemb_w[c0 + r];
        wB[r] = pemb_b[c0 + r] + eemb_b[c0 + r];
        wC[r] = eemb_w[c0 + r];
    }
    const float* fm_b = frame_mask + (size_t)b * TF;
    const float* lc_b = log_cf0 + (size_t)b * TF;
    const float* en_b = energy + (size_t)b * TF;
    float* ob = out + ((size_t)b * CC + c0) * TF;
    int fbase = wv * 512;

#pragma unroll
    for (int it = 0; it < 2; ++it) {
        int f0 = fbase + it * 256 + lane;  // component k handles frame f0 + 64k
        int p[4], pcl[4];
        float fmv[4], xm[4], lcv[4], env[4];
#pragma unroll
        for (int k = 0; k < 4; ++k) {
            int f = f0 + 64 * k;
            p[k] = po16[f];  // sign-extends; -1 = unmapped frame
            pcl[k] = imax(p[k], 0);
            float fm = fm_b[f];
            fmv[k] = fm;
            xm[k] = (p[k] >= 0 ? pm_s[pcl[k]] : 0.f) * fm;
            lcv[k] = lc_b[f];
            env[k] = en_b[f];
        }
#pragma unroll
        for (int r = 0; r < 16; ++r) {
            const float* xsr = xs + r * TP;
            float* obr = ob + (size_t)r * TF + f0;
#pragma unroll
            for (int k = 0; k < 4; ++k) {
                float xv = xsr[pcl[k]];  // <=2-way bank aliasing
                float t = __builtin_fmaf(lcv[k], wA[r], wB[r]);
                t = __builtin_fmaf(env[k], wC[r], t);
                float o = __builtin_fmaf(xv, xm[k], t * fmv[k]);
                __builtin_nontemporal_store(o, obr + 64 * k);
            }
        }
    }
}

extern "C" void kernel_launch(void* const* d_in, const int* in_sizes, int n_in,
                              void* d_out, int out_size, void* d_ws, size_t ws_size,
                              hipStream_t stream) {
    const float* x          = (const float*)d_in[0];
    const float* phone_mask = (const float*)d_in[1];
    const float* frame_mask = (const float*)d_in[2];
    const int*   duration   = (const int*)d_in[3];
    const float* log_cf0    = (const float*)d_in[4];
    const float* energy     = (const float*)d_in[6];
    const float* dur_w      = (const float*)d_in[7];
    const float* dur_b      = (const float*)d_in[8];
    const float* pitch_w    = (const float*)d_in[9];
    const float* pitch_b    = (const float*)d_in[10];
    const float* pemb_w     = (const float*)d_in[11];
    const float* pemb_b     = (const float*)d_in[12];
    const float* enp_w      = (const float*)d_in[13];
    const float* enp_b      = (const float*)d_in[14];
    const float* eemb_w     = (const float*)d_in[15];
    const float* eemb_b     = (const float*)d_in[16];

    float* out = (float*)d_out;
    float* ldp = out + (size_t)BB * CC * TF;
    float* lcp = ldp + (size_t)BB * TP;
    float* vup = lcp + (size_t)BB * TF;
    float* epp = vup + (size_t)BB * TF;

    // workspace: partials [BB][NJ][4][TP] floats, then BB arrival counters
    float* ws_part = (float*)d_ws;
    int* ws_ctr = (int*)((char*)d_ws + (size_t)BB * NJ * 4 * TP * sizeof(float));
    hipMemsetAsync(ws_ctr, 0, BB * sizeof(int), stream);  // in-graph, per replay

    mono_kernel<<<dim3(NJ, BB), dim3(256), 0, stream>>>(
        x, phone_mask, frame_mask, duration, log_cf0, energy, dur_w, dur_b,
        pitch_w, pitch_b, pemb_w, pemb_b, enp_w, enp_b, eemb_w, eemb_b,
        ws_part, ws_ctr, out, ldp, lcp, vup, epp);
}

// Round 4
// 31.654 us; speedup vs baseline: 4.5838x; 4.5838x over previous
//
#include <hip/hip_runtime.h>

#define BB 32
#define CC 384
#define TP 512
#define TF 2048

__device__ __forceinline__ int imax(int a, int b) { return a > b ? a : b; }
__device__ __forceinline__ int imin(int a, int b) { return a < b ? a : b; }

// One kernel, no inter-block dependencies. Grid (32, BB), 256 threads.
//  j<24 : stream 16 c-rows of out. NEW: per-thread register cache of the
//         frame-gather data (8 frames/thread, stride-256 mapping), then the
//         row loop is OUTERMOST so each block writes its contiguous 128 KB
//         out-region in strictly ascending address order (DRAM row locality,
//         fillBuffer-style) instead of interleaving 16 rows in 256B hops.
//  j>=24: phone-space GEMV (y kept in LDS) + ldp + frame preds for this
//         block's contiguous frame window; jj==7 also writes the tail.
__global__ __launch_bounds__(256, 4) void mono_kernel(
    const float* __restrict__ x, const float* __restrict__ phone_mask,
    const float* __restrict__ frame_mask, const int* __restrict__ duration,
    const float* __restrict__ log_cf0, const float* __restrict__ energy,
    const float* __restrict__ dur_w, const float* __restrict__ dur_b,
    const float* __restrict__ pitch_w, const float* __restrict__ pitch_b,
    const float* __restrict__ pemb_w, const float* __restrict__ pemb_b,
    const float* __restrict__ enp_w, const float* __restrict__ enp_b,
    const float* __restrict__ eemb_w, const float* __restrict__ eemb_b,
    float* __restrict__ out, float* __restrict__ ldp, float* __restrict__ lcp,
    float* __restrict__ vup, float* __restrict__ epp) {
    int b = blockIdx.y;
    int j = blockIdx.x;
    int tid = threadIdx.x;
    int lane = tid & 63;
    int wv = tid >> 6;  // 0..3
    const float* xb = x + (size_t)b * CC * TP;

    if (j < 24) {
        // ---------------- stream block ----------------
        __shared__ short po16[TF];    // 4 KB frame->phone
        __shared__ int ps[256];       // 1 KB pair-scan
        __shared__ float xs[16 * TP]; // 32 KB staged (x * phone_mask) rows
        int c0 = __builtin_amdgcn_readfirstlane(j * 16);
        const float* src = xb + (size_t)c0 * TP;
        const float* pmb = phone_mask + (size_t)b * TP;
        // linear staging: conflict-free LDS writes, coalesced 1 KB/wave-instr
#pragma unroll
        for (int q = 0; q < 8; ++q) {
            int off = q * 1024 + tid * 4;
            float4 v = *(const float4*)(src + off);
            float4 m = *(const float4*)(pmb + (off & (TP - 1)));
            v.x *= m.x; v.y *= m.y; v.z *= m.z; v.w *= m.w;
            *(float4*)(xs + off) = v;
        }

        int2 d01 = *(const int2*)(duration + b * TP + 2 * tid);
        int d0 = d01.x, d1 = d01.y;
        ps[tid] = d0 + d1;
#pragma unroll
        for (int h = 0; h < 4; ++h) ((int*)po16)[tid + 256 * h] = -1;  // two -1 shorts
        __syncthreads();
        for (int off = 1; off < 256; off <<= 1) {
            int v = (tid >= off) ? ps[tid - off] : 0;
            __syncthreads();
            ps[tid] += v;
            __syncthreads();
        }
        int excl = tid ? ps[tid - 1] : 0;
        int e0 = imin(excl + d0, TF);
        int e1 = imin(excl + d0 + d1, TF);
        for (int f = imin(excl, TF); f < e0; ++f) po16[f] = (short)(2 * tid);
        for (int f = e0; f < e1; ++f) po16[f] = (short)(2 * tid + 1);
        __syncthreads();

        // ---- register-cache frame data: thread owns frames f = q*256 + tid ----
        const float* fm_b = frame_mask + (size_t)b * TF;
        const float* lc_b = log_cf0 + (size_t)b * TF;
        const float* en_b = energy + (size_t)b * TF;
        int pcl[8];
        float selfm[8], fmv[8], lcv[8], env[8];
#pragma unroll
        for (int q = 0; q < 8; ++q) {
            int f = q * 256 + tid;
            int p = po16[f];            // lane-consecutive shorts: conflict-free
            int pc = imax(p, 0);
            pcl[q] = pc;
            float fm = fm_b[f];
            fmv[q] = fm;
            selfm[q] = (p >= 0) ? fm : 0.f;
            lcv[q] = lc_b[f];
            env[q] = en_b[f];
        }

        float wA[16], wB[16], wC[16];
#pragma unroll
        for (int r = 0; r < 16; ++r) {
            wA[r] = pemb_w[c0 + r];
            wB[r] = pemb_b[c0 + r] + eemb_b[c0 + r];
            wC[r] = eemb_w[c0 + r];
        }
        float* ob = out + ((size_t)b * CC + c0) * TF;

        // ---- row-major store sweep: ascending addresses over 128 KB ----
#pragma unroll
        for (int r = 0; r < 16; ++r) {
            const float* xsr = xs + r * TP;
            float* obr = ob + (size_t)r * TF + tid;
            float sA = wA[r], sB = wB[r], sC = wC[r];
#pragma unroll
            for (int q = 0; q < 8; ++q) {
                float xv = xsr[pcl[q]];               // <=2-way bank aliasing
                float t = __builtin_fmaf(lcv[q], sA, sB);
                t = __builtin_fmaf(env[q], sC, t);
                float o = __builtin_fmaf(xv, selfm[q], t * fmv[q]);
                __builtin_nontemporal_store(o, obr + q * 256);
            }
        }
    } else {
        // ---------------- GEMV + preds block ----------------
        int jj = j - 24;  // 0..7, phones [jj*64, jj*64+64)
        __shared__ float r[16 * 64];
        __shared__ int ps[256];
        __shared__ float y_lds[3 * 64];
        __shared__ float pm_lds[64];
        __shared__ short po_win[192];
        int t = jj * 64 + lane;
        float a0 = 0.f, a1 = 0.f, a2 = 0.f, a3 = 0.f;
#pragma unroll 8
        for (int i = 0; i < CC / 4; ++i) {
            int c = __builtin_amdgcn_readfirstlane(wv + 4 * i);
            float xv = xb[c * TP + t];
            a0 += xv * pitch_w[c];
            a1 += xv * pitch_w[CC + c];
            a2 += xv * enp_w[c];
            a3 += xv * dur_w[c];
        }
        r[(0 * 4 + wv) * 64 + lane] = a0;
        r[(1 * 4 + wv) * 64 + lane] = a1;
        r[(2 * 4 + wv) * 64 + lane] = a2;
        r[(3 * 4 + wv) * 64 + lane] = a3;
        int2 d01 = *(const int2*)(duration + b * TP + 2 * tid);
        int d0 = d01.x, d1 = d01.y;
        ps[tid] = d0 + d1;
        if (tid < 64) pm_lds[tid] = phone_mask[b * TP + jj * 64 + tid];
        __syncthreads();
        for (int off = 1; off < 256; off <<= 1) {
            int v = (tid >= off) ? ps[tid - off] : 0;
            __syncthreads();
            ps[tid] += v;
            __syncthreads();
        }
        // y reduce: wave wv owns output o=wv
        float a = 0.f;
#pragma unroll
        for (int k = 0; k < 4; ++k) a += r[(wv * 4 + k) * 64 + lane];
        if (wv == 3)
            ldp[b * TP + t] = (a + dur_b[0]) * pm_lds[lane];
        else
            y_lds[wv * 64 + lane] = a;
        // window scatter by the 32 owning pair-threads
        int base_lo = (jj > 0) ? imin(ps[jj * 32 - 1], TF) : 0;
        int base_hi = imin(ps[(jj + 1) * 32 - 1], TF);
        if (tid >= jj * 32 && tid < (jj + 1) * 32) {
            int excl = tid ? ps[tid - 1] : 0;
            int e0 = imin(excl + d0, TF);
            int e1 = imin(excl + d0 + d1, TF);
            for (int f = imin(excl, TF); f < e0; ++f) po_win[f - base_lo] = (short)(2 * tid - jj * 64);
            for (int f = e0; f < e1; ++f) po_win[f - base_lo] = (short)(2 * tid + 1 - jj * 64);
        }
        int total = imin(ps[255], TF);
        __syncthreads();
        int win = base_hi - base_lo;
        for (int idx = tid; idx < win; idx += 256) {
            int f = base_lo + idx;
            int p = po_win[idx];
            float fm = frame_mask[b * TF + f];
            float xm = pm_lds[p] * fm;
            lcp[b * TF + f] = (y_lds[p] * xm + pitch_b[0]) * fm;
            vup[b * TF + f] = (y_lds[64 + p] * xm + pitch_b[1]) * fm;
            epp[b * TF + f] = (y_lds[128 + p] * xm + enp_b[0]) * fm;
        }
        if (jj == 7) {
            for (int f = total + tid; f < TF; f += 256) {
                float fm = frame_mask[b * TF + f];
                lcp[b * TF + f] = pitch_b[0] * fm;
                vup[b * TF + f] = pitch_b[1] * fm;
                epp[b * TF + f] = enp_b[0] * fm;
            }
        }
    }
}

extern "C" void kernel_launch(void* const* d_in, const int* in_sizes, int n_in,
                              void* d_out, int out_size, void* d_ws, size_t ws_size,
                              hipStream_t stream) {
    const float* x          = (const float*)d_in[0];
    const float* phone_mask = (const float*)d_in[1];
    const float* frame_mask = (const float*)d_in[2];
    const int*   duration   = (const int*)d_in[3];
    const float* log_cf0    = (const float*)d_in[4];
    const float* energy     = (const float*)d_in[6];
    const float* dur_w      = (const float*)d_in[7];
    const float* dur_b      = (const float*)d_in[8];
    const float* pitch_w    = (const float*)d_in[9];
    const float* pitch_b    = (const float*)d_in[10];
    const float* pemb_w     = (const float*)d_in[11];
    const float* pemb_b     = (const float*)d_in[12];
    const float* enp_w      = (const float*)d_in[13];
    const float* enp_b      = (const float*)d_in[14];
    const float* eemb_w     = (const float*)d_in[15];
    const float* eemb_b     = (const float*)d_in[16];

    float* out = (float*)d_out;
    float* ldp = out + (size_t)BB * CC * TF;
    float* lcp = ldp + (size_t)BB * TP;
    float* vup = lcp + (size_t)BB * TF;
    float* epp = vup + (size_t)BB * TF;

    mono_kernel<<<dim3(32, BB), dim3(256), 0, stream>>>(
        x, phone_mask, frame_mask, duration, log_cf0, energy, dur_w, dur_b,
        pitch_w, pitch_b, pemb_w, pemb_b, enp_w, enp_b, eemb_w, eemb_b,
        out, ldp, lcp, vup, epp);
}

// Round 5
// 29.584 us; speedup vs baseline: 4.9045x; 1.0700x over previous
//
#include <hip/hip_runtime.h>

#define BB 32
#define CC 384
#define TP 512
#define TF 2048

__device__ __forceinline__ int imax(int a, int b) { return a > b ? a : b; }
__device__ __forceinline__ int imin(int a, int b) { return a < b ? a : b; }

// One kernel, no inter-block dependencies. Grid (32, BB), 256 threads.
//  j<24 : stream 16 c-rows of out. NEW vs R4: NO LDS staging of x — the
//         frame gather reads x directly from global. 64 consecutive frames
//         map to ~43 consecutive phones (mean dur 1.5), so each gather
//         wave-instruction touches ~172 contiguous bytes: 2-3 cache lines,
//         served by L1 (32 KB = block working set) / L2 / L3. This removes
//         the 32 KB global->VGPR->LDS round-trip, the LDS-pipe gather time
//         (~12K cyc/CU), and lets stores start right after the scan.
//         fm/lc/en register-cache loads are hoisted BEFORE the scan so their
//         latency hides under the scan barriers.
//  j>=24: phone-space GEMV (y kept in LDS) + ldp + frame preds for this
//         block's contiguous frame window; jj==7 also writes the tail.
__global__ __launch_bounds__(256, 4) void mono_kernel(
    const float* __restrict__ x, const float* __restrict__ phone_mask,
    const float* __restrict__ frame_mask, const int* __restrict__ duration,
    const float* __restrict__ log_cf0, const float* __restrict__ energy,
    const float* __restrict__ dur_w, const float* __restrict__ dur_b,
    const float* __restrict__ pitch_w, const float* __restrict__ pitch_b,
    const float* __restrict__ pemb_w, const float* __restrict__ pemb_b,
    const float* __restrict__ enp_w, const float* __restrict__ enp_b,
    const float* __restrict__ eemb_w, const float* __restrict__ eemb_b,
    float* __restrict__ out, float* __restrict__ ldp, float* __restrict__ lcp,
    float* __restrict__ vup, float* __restrict__ epp) {
    int b = blockIdx.y;
    int j = blockIdx.x;
    int tid = threadIdx.x;
    int lane = tid & 63;
    int wv = tid >> 6;  // 0..3
    const float* xb = x + (size_t)b * CC * TP;

    if (j < 24) {
        // ---------------- stream block ----------------
        __shared__ short po16[TF];  // 4 KB frame->phone
        __shared__ int ps[256];     // 1 KB pair-scan
        __shared__ float pm_s[TP];  // 2 KB phone_mask row
        int c0 = __builtin_amdgcn_readfirstlane(j * 16);

        // ---- early independent loads: frame data into registers, pm into LDS
        const float* fm_b = frame_mask + (size_t)b * TF;
        const float* lc_b = log_cf0 + (size_t)b * TF;
        const float* en_b = energy + (size_t)b * TF;
        float fmv[8], lcv[8], env[8];
#pragma unroll
        for (int q = 0; q < 8; ++q) {
            int f = q * 256 + tid;
            fmv[q] = fm_b[f];
            lcv[q] = lc_b[f];
            env[q] = en_b[f];
        }
        pm_s[tid] = phone_mask[b * TP + tid];
        pm_s[tid + 256] = phone_mask[b * TP + tid + 256];

        int2 d01 = *(const int2*)(duration + b * TP + 2 * tid);
        int d0 = d01.x, d1 = d01.y;
        ps[tid] = d0 + d1;
#pragma unroll
        for (int h = 0; h < 4; ++h) ((int*)po16)[tid + 256 * h] = -1;  // two -1 shorts
        __syncthreads();
        for (int off = 1; off < 256; off <<= 1) {
            int v = (tid >= off) ? ps[tid - off] : 0;
            __syncthreads();
            ps[tid] += v;
            __syncthreads();
        }
        int excl = tid ? ps[tid - 1] : 0;
        int e0 = imin(excl + d0, TF);
        int e1 = imin(excl + d0 + d1, TF);
        for (int f = imin(excl, TF); f < e0; ++f) po16[f] = (short)(2 * tid);
        for (int f = e0; f < e1; ++f) po16[f] = (short)(2 * tid + 1);
        __syncthreads();

        // ---- po16-dependent register cache: gather index + combined mask
        int pcl[8];
        float xm[8];
#pragma unroll
        for (int q = 0; q < 8; ++q) {
            int f = q * 256 + tid;
            int p = po16[f];  // lane-consecutive shorts: conflict-free
            int pc = imax(p, 0);
            pcl[q] = pc;
            xm[q] = (p >= 0 ? pm_s[pc] : 0.f) * fmv[q];
        }

        float wA[16], wB[16], wC[16];
#pragma unroll
        for (int r = 0; r < 16; ++r) {
            wA[r] = pemb_w[c0 + r];
            wB[r] = pemb_b[c0 + r] + eemb_b[c0 + r];
            wC[r] = eemb_w[c0 + r];
        }
        float* ob = out + ((size_t)b * CC + c0) * TF;

        // ---- row-major sweep: direct global gather, ascending-address stores
#pragma unroll
        for (int r = 0; r < 16; ++r) {
            const float* xr = xb + (size_t)(c0 + r) * TP;
            float* obr = ob + (size_t)r * TF + tid;
            float sA = wA[r], sB = wB[r], sC = wC[r];
#pragma unroll
            for (int q = 0; q < 8; ++q) {
                float xv = xr[pcl[q]];  // ~172B span per wave-instr: 2-3 lines
                float t = __builtin_fmaf(lcv[q], sA, sB);
                t = __builtin_fmaf(env[q], sC, t);
                float o = __builtin_fmaf(xv, xm[q], t * fmv[q]);
                __builtin_nontemporal_store(o, obr + q * 256);
            }
        }
    } else {
        // ---------------- GEMV + preds block ----------------
        int jj = j - 24;  // 0..7, phones [jj*64, jj*64+64)
        __shared__ float r[16 * 64];
        __shared__ int ps[256];
        __shared__ float y_lds[3 * 64];
        __shared__ float pm_lds[64];
        __shared__ short po_win[192];
        int t = jj * 64 + lane;
        float a0 = 0.f, a1 = 0.f, a2 = 0.f, a3 = 0.f;
#pragma unroll 8
        for (int i = 0; i < CC / 4; ++i) {
            int c = __builtin_amdgcn_readfirstlane(wv + 4 * i);
            float xv = xb[c * TP + t];
            a0 += xv * pitch_w[c];
            a1 += xv * pitch_w[CC + c];
            a2 += xv * enp_w[c];
            a3 += xv * dur_w[c];
        }
        r[(0 * 4 + wv) * 64 + lane] = a0;
        r[(1 * 4 + wv) * 64 + lane] = a1;
        r[(2 * 4 + wv) * 64 + lane] = a2;
        r[(3 * 4 + wv) * 64 + lane] = a3;
        int2 d01 = *(const int2*)(duration + b * TP + 2 * tid);
        int d0 = d01.x, d1 = d01.y;
        ps[tid] = d0 + d1;
        if (tid < 64) pm_lds[tid] = phone_mask[b * TP + jj * 64 + tid];
        __syncthreads();
        for (int off = 1; off < 256; off <<= 1) {
            int v = (tid >= off) ? ps[tid - off] : 0;
            __syncthreads();
            ps[tid] += v;
            __syncthreads();
        }
        // y reduce: wave wv owns output o=wv
        float a = 0.f;
#pragma unroll
        for (int k = 0; k < 4; ++k) a += r[(wv * 4 + k) * 64 + lane];
        if (wv == 3)
            ldp[b * TP + t] = (a + dur_b[0]) * pm_lds[lane];
        else
            y_lds[wv * 64 + lane] = a;
        // window scatter by the 32 owning pair-threads
        int base_lo = (jj > 0) ? imin(ps[jj * 32 - 1], TF) : 0;
        int base_hi = imin(ps[(jj + 1) * 32 - 1], TF);
        if (tid >= jj * 32 && tid < (jj + 1) * 32) {
            int excl = tid ? ps[tid - 1] : 0;
            int e0 = imin(excl + d0, TF);
            int e1 = imin(excl + d0 + d1, TF);
            for (int f = imin(excl, TF); f < e0; ++f) po_win[f - base_lo] = (short)(2 * tid - jj * 64);
            for (int f = e0; f < e1; ++f) po_win[f - base_lo] = (short)(2 * tid + 1 - jj * 64);
        }
        int total = imin(ps[255], TF);
        __syncthreads();
        int win = base_hi - base_lo;
        for (int idx = tid; idx < win; idx += 256) {
            int f = base_lo + idx;
            int p = po_win[idx];
            float fm = frame_mask[b * TF + f];
            float xm = pm_lds[p] * fm;
            lcp[b * TF + f] = (y_lds[p] * xm + pitch_b[0]) * fm;
            vup[b * TF + f] = (y_lds[64 + p] * xm + pitch_b[1]) * fm;
            epp[b * TF + f] = (y_lds[128 + p] * xm + enp_b[0]) * fm;
        }
        if (jj == 7) {
            for (int f = total + tid; f < TF; f += 256) {
                float fm = frame_mask[b * TF + f];
                lcp[b * TF + f] = pitch_b[0] * fm;
                vup[b * TF + f] = pitch_b[1] * fm;
                epp[b * TF + f] = enp_b[0] * fm;
            }
        }
    }
}

extern "C" void kernel_launch(void* const* d_in, const int* in_sizes, int n_in,
                              void* d_out, int out_size, void* d_ws, size_t ws_size,
                              hipStream_t stream) {
    const float* x          = (const float*)d_in[0];
    const float* phone_mask = (const float*)d_in[1];
    const float* frame_mask = (const float*)d_in[2];
    const int*   duration   = (const int*)d_in[3];
    const float* log_cf0    = (const float*)d_in[4];
    const float* energy     = (const float*)d_in[6];
    const float* dur_w      = (const float*)d_in[7];
    const float* dur_b      = (const float*)d_in[8];
    const float* pitch_w    = (const float*)d_in[9];
    const float* pitch_b    = (const float*)d_in[10];
    const float* pemb_w     = (const float*)d_in[11];
    const float* pemb_b     = (const float*)d_in[12];
    const float* enp_w      = (const float*)d_in[13];
    const float* enp_b      = (const float*)d_in[14];
    const float* eemb_w     = (const float*)d_in[15];
    const float* eemb_b     = (const float*)d_in[16];

    float* out = (float*)d_out;
    float* ldp = out + (size_t)BB * CC * TF;
    float* lcp = ldp + (size_t)BB * TP;
    float* vup = lcp + (size_t)BB * TF;
    float* epp = vup + (size_t)BB * TF;

    mono_kernel<<<dim3(32, BB), dim3(256), 0, stream>>>(
        x, phone_mask, frame_mask, duration, log_cf0, energy, dur_w, dur_b,
        pitch_w, pitch_b, pemb_w, pemb_b, enp_w, enp_b, eemb_w, eemb_b,
        out, ldp, lcp, vup, epp);
}

// Round 6
// 29.184 us; speedup vs baseline: 4.9716x; 1.0137x over previous
//
#include <hip/hip_runtime.h>

#define BB 32
#define CC 384
#define TP 512
#define TF 2048

typedef float f32x4 __attribute__((ext_vector_type(4)));

__device__ __forceinline__ int imax(int a, int b) { return a > b ? a : b; }
__device__ __forceinline__ int imin(int a, int b) { return a < b ? a : b; }

// One kernel, no inter-block dependencies. Grid (32, BB), 256 threads.
//  j<24 : stream 16 c-rows of out, direct global gather of x (no LDS staging).
//         NEW vs R5: (a) wave-shuffle scan (6 shfl_up, 2 barriers total) replaces
//         the 16-barrier Hillis-Steele; (b) frame->thread map f = q*1024+4*tid+k
//         so po16 reads are short4, fm/lc/en loads are float4, and stores are
//         float4 nontemporal (1024B contiguous per wave-instr, fillBuffer-style).
//  j>=24: phone-space GEMV (y kept in LDS) + ldp + frame preds for this
//         block's contiguous frame window; jj==7 also writes the tail.
__global__ __launch_bounds__(256, 4) void mono_kernel(
    const float* __restrict__ x, const float* __restrict__ phone_mask,
    const float* __restrict__ frame_mask, const int* __restrict__ duration,
    const float* __restrict__ log_cf0, const float* __restrict__ energy,
    const float* __restrict__ dur_w, const float* __restrict__ dur_b,
    const float* __restrict__ pitch_w, const float* __restrict__ pitch_b,
    const float* __restrict__ pemb_w, const float* __restrict__ pemb_b,
    const float* __restrict__ enp_w, const float* __restrict__ enp_b,
    const float* __restrict__ eemb_w, const float* __restrict__ eemb_b,
    float* __restrict__ out, float* __restrict__ ldp, float* __restrict__ lcp,
    float* __restrict__ vup, float* __restrict__ epp) {
    int b = blockIdx.y;
    int j = blockIdx.x;
    int tid = threadIdx.x;
    int lane = tid & 63;
    int wv = tid >> 6;  // 0..3
    const float* xb = x + (size_t)b * CC * TP;

    if (j < 24) {
        // ---------------- stream block ----------------
        __shared__ short po16[TF];  // 4 KB frame->phone
        __shared__ float pm_s[TP];  // 2 KB phone_mask row
        __shared__ int wsum[4];     // per-wave scan totals
        int c0 = __builtin_amdgcn_readfirstlane(j * 16);

        // ---- early independent loads (latency hides under scan) ----
        const float* fm_b = frame_mask + (size_t)b * TF;
        const float* lc_b = log_cf0 + (size_t)b * TF;
        const float* en_b = energy + (size_t)b * TF;
        float fmv[8], lcv[8], env[8];
#pragma unroll
        for (int q = 0; q < 2; ++q) {
            int f = q * 1024 + 4 * tid;
            float4 fm4 = *(const float4*)(fm_b + f);
            float4 lc4 = *(const float4*)(lc_b + f);
            float4 en4 = *(const float4*)(en_b + f);
            fmv[4 * q + 0] = fm4.x; fmv[4 * q + 1] = fm4.y; fmv[4 * q + 2] = fm4.z; fmv[4 * q + 3] = fm4.w;
            lcv[4 * q + 0] = lc4.x; lcv[4 * q + 1] = lc4.y; lcv[4 * q + 2] = lc4.z; lcv[4 * q + 3] = lc4.w;
            env[4 * q + 0] = en4.x; env[4 * q + 1] = en4.y; env[4 * q + 2] = en4.z; env[4 * q + 3] = en4.w;
        }
        pm_s[tid] = phone_mask[b * TP + tid];
        pm_s[tid + 256] = phone_mask[b * TP + tid + 256];
        int2 d01 = *(const int2*)(duration + b * TP + 2 * tid);
        int d0 = d01.x, d1 = d01.y;
#pragma unroll
        for (int h = 0; h < 4; ++h) ((int*)po16)[tid + 256 * h] = -1;  // two -1 shorts

        // ---- wave-shuffle inclusive scan of pair sums ----
        int s = d0 + d1;
        int v = s;
#pragma unroll
        for (int off = 1; off < 64; off <<= 1) {
            int t = __shfl_up(v, off, 64);
            if (lane >= off) v += t;
        }
        if (lane == 63) wsum[wv] = v;
        __syncthreads();  // wsum + po16 fill + pm_s ready
        int base = 0;
#pragma unroll
        for (int w = 0; w < 4; ++w) base += (w < wv) ? wsum[w] : 0;
        int excl = base + v - s;

        int e0 = imin(excl + d0, TF);
        int e1 = imin(excl + d0 + d1, TF);
        for (int f = imin(excl, TF); f < e0; ++f) po16[f] = (short)(2 * tid);
        for (int f = e0; f < e1; ++f) po16[f] = (short)(2 * tid + 1);
        __syncthreads();

        // ---- po16-dependent register cache: gather index + combined mask ----
        int pcl[8];
        float xm[8];
#pragma unroll
        for (int q = 0; q < 2; ++q) {
            short4 p4 = *(const short4*)(po16 + q * 1024 + 4 * tid);
            short pk[4] = {p4.x, p4.y, p4.z, p4.w};
#pragma unroll
            for (int k = 0; k < 4; ++k) {
                int p = pk[k];
                int pc = imax(p, 0);
                pcl[4 * q + k] = pc;
                xm[4 * q + k] = (p >= 0 ? pm_s[pc] : 0.f) * fmv[4 * q + k];
            }
        }

        float wA[16], wB[16], wC[16];
#pragma unroll
        for (int r = 0; r < 16; ++r) {
            wA[r] = pemb_w[c0 + r];
            wB[r] = pemb_b[c0 + r] + eemb_b[c0 + r];
            wC[r] = eemb_w[c0 + r];
        }
        float* ob = out + ((size_t)b * CC + c0) * TF;

        // ---- row-major sweep: global gather, float4 nt stores (1KB/wave-instr) ----
#pragma unroll
        for (int r = 0; r < 16; ++r) {
            const float* xr = xb + (size_t)(c0 + r) * TP;
            float* obr = ob + (size_t)r * TF;
            float sA = wA[r], sB = wB[r], sC = wC[r];
#pragma unroll
            for (int q = 0; q < 2; ++q) {
                f32x4 o;
#pragma unroll
                for (int k = 0; k < 4; ++k) {
                    int i = 4 * q + k;
                    float xv = xr[pcl[i]];
                    float t = __builtin_fmaf(lcv[i], sA, sB);
                    t = __builtin_fmaf(env[i], sC, t);
                    o[k] = __builtin_fmaf(xv, xm[i], t * fmv[i]);
                }
                __builtin_nontemporal_store(o, (f32x4*)(obr + q * 1024 + 4 * tid));
            }
        }
    } else {
        // ---------------- GEMV + preds block ----------------
        int jj = j - 24;  // 0..7, phones [jj*64, jj*64+64)
        __shared__ float r[16 * 64];
        __shared__ int ps[256];
        __shared__ float y_lds[3 * 64];
        __shared__ float pm_lds[64];
        __shared__ short po_win[192];
        __shared__ int wsumg[4];
        int t = jj * 64 + lane;
        float a0 = 0.f, a1 = 0.f, a2 = 0.f, a3 = 0.f;
#pragma unroll 8
        for (int i = 0; i < CC / 4; ++i) {
            int c = __builtin_amdgcn_readfirstlane(wv + 4 * i);
            float xv = xb[c * TP + t];
            a0 += xv * pitch_w[c];
            a1 += xv * pitch_w[CC + c];
            a2 += xv * enp_w[c];
            a3 += xv * dur_w[c];
        }
        r[(0 * 4 + wv) * 64 + lane] = a0;
        r[(1 * 4 + wv) * 64 + lane] = a1;
        r[(2 * 4 + wv) * 64 + lane] = a2;
        r[(3 * 4 + wv) * 64 + lane] = a3;
        int2 d01 = *(const int2*)(duration + b * TP + 2 * tid);
        int d0 = d01.x, d1 = d01.y;
        if (tid < 64) pm_lds[tid] = phone_mask[b * TP + jj * 64 + tid];

        // wave-shuffle scan -> inclusive sums into ps[tid]
        int s = d0 + d1;
        int v = s;
#pragma unroll
        for (int off = 1; off < 64; off <<= 1) {
            int tt = __shfl_up(v, off, 64);
            if (lane >= off) v += tt;
        }
        if (lane == 63) wsumg[wv] = v;
        __syncthreads();  // r[], pm_lds, wsumg ready
        int base = 0;
#pragma unroll
        for (int w = 0; w < 4; ++w) base += (w < wv) ? wsumg[w] : 0;
        ps[tid] = base + v;
        __syncthreads();  // ps visible

        // y reduce: wave wv owns output o=wv
        float a = 0.f;
#pragma unroll
        for (int k = 0; k < 4; ++k) a += r[(wv * 4 + k) * 64 + lane];
        if (wv == 3)
            ldp[b * TP + t] = (a + dur_b[0]) * pm_lds[lane];
        else
            y_lds[wv * 64 + lane] = a;
        // window scatter by the 32 owning pair-threads
        int base_lo = (jj > 0) ? imin(ps[jj * 32 - 1], TF) : 0;
        int base_hi = imin(ps[(jj + 1) * 32 - 1], TF);
        if (tid >= jj * 32 && tid < (jj + 1) * 32) {
            int excl = tid ? ps[tid - 1] : 0;
            int e0 = imin(excl + d0, TF);
            int e1 = imin(excl + d0 + d1, TF);
            for (int f = imin(excl, TF); f < e0; ++f) po_win[f - base_lo] = (short)(2 * tid - jj * 64);
            for (int f = e0; f < e1; ++f) po_win[f - base_lo] = (short)(2 * tid + 1 - jj * 64);
        }
        int total = imin(ps[255], TF);
        __syncthreads();
        int win = base_hi - base_lo;
        for (int idx = tid; idx < win; idx += 256) {
            int f = base_lo + idx;
            int p = po_win[idx];
            float fm = frame_mask[b * TF + f];
            float xm = pm_lds[p] * fm;
            lcp[b * TF + f] = (y_lds[p] * xm + pitch_b[0]) * fm;
            vup[b * TF + f] = (y_lds[64 + p] * xm + pitch_b[1]) * fm;
            epp[b * TF + f] = (y_lds[128 + p] * xm + enp_b[0]) * fm;
        }
        if (jj == 7) {
            for (int f = total + tid; f < TF; f += 256) {
                float fm = frame_mask[b * TF + f];
                lcp[b * TF + f] = pitch_b[0] * fm;
                vup[b * TF + f] = pitch_b[1] * fm;
                epp[b * TF + f] = enp_b[0] * fm;
            }
        }
    }
}

extern "C" void kernel_launch(void* const* d_in, const int* in_sizes, int n_in,
                              void* d_out, int out_size, void* d_ws, size_t ws_size,
                              hipStream_t stream) {
    const float* x          = (const float*)d_in[0];
    const float* phone_mask = (const float*)d_in[1];
    const float* frame_mask = (const float*)d_in[2];
    const int*   duration   = (const int*)d_in[3];
    const float* log_cf0    = (const float*)d_in[4];
    const float* energy     = (const float*)d_in[6];
    const float* dur_w      = (const float*)d_in[7];
    const float* dur_b      = (const float*)d_in[8];
    const float* pitch_w    = (const float*)d_in[9];
    const float* pitch_b    = (const float*)d_in[10];
    const float* pemb_w     = (const float*)d_in[11];
    const float* pemb_b     = (const float*)d_in[12];
    const float* enp_w      = (const float*)d_in[13];
    const float* enp_b      = (const float*)d_in[14];
    const float* eemb_w     = (const float*)d_in[15];
    const float* eemb_b     = (const float*)d_in[16];

    float* out = (float*)d_out;
    float* ldp = out + (size_t)BB * CC * TF;
    float* lcp = ldp + (size_t)BB * TP;
    float* vup = lcp + (size_t)BB * TF;
    float* epp = vup + (size_t)BB * TF;

    mono_kernel<<<dim3(32, BB), dim3(256), 0, stream>>>(
        x, phone_mask, frame_mask, duration, log_cf0, energy, dur_w, dur_b,
        pitch_w, pitch_b, pemb_w, pemb_b, enp_w, enp_b, eemb_w, eemb_b,
        out, ldp, lcp, vup, epp);
}